// Round 1
// baseline (380.874 us; speedup 1.0000x reference)
//
#include <hip/hip_runtime.h>
#include <math.h>

#define SL 2048   // sequence length L
#define NB 32     // batch
#define NH 128    // feature dim H
#define NP 256    // state dim P

// ---------------------------------------------------------------------------
// Kernel 1: Bu[b][p][l] (complex interleaved) = f_p * (u[l,b,:] . B_tilde[p,:])
// Tiled fp32 GEMM. Block: 256 thr, tile l=64 x p=64, K=128 in chunks of 32.
// Per-thread 4l x 4p complex accumulators.
// ---------------------------------------------------------------------------
__global__ __launch_bounds__(256) void k_bu(
    const float* __restrict__ u, const float* __restrict__ Btr,
    const float* __restrict__ Bti, const float* __restrict__ logLr,
    const float* __restrict__ Lim, const float* __restrict__ logDt,
    float* __restrict__ bu)
{
    __shared__ __attribute__((aligned(16))) float u_s[32][68];   // [h][l]
    __shared__ __attribute__((aligned(16))) float br_s[32][68];  // [h][p]
    __shared__ __attribute__((aligned(16))) float bi_s[32][68];  // [h][p]

    const int l0 = blockIdx.x * 64;
    const int p0 = blockIdx.y * 64;
    const int b  = blockIdx.z;
    const int tid = threadIdx.x;
    const int lsub = (tid & 15) * 4;
    const int psub = (tid >> 4) * 4;
    const int row = tid >> 2;        // 0..63
    const int j0  = (tid & 3) * 8;   // 0,8,16,24

    float accr[4][4], acci[4][4];
    #pragma unroll
    for (int i = 0; i < 4; ++i)
        #pragma unroll
        for (int j = 0; j < 4; ++j) { accr[i][j] = 0.f; acci[i][j] = 0.f; }

    for (int h0 = 0; h0 < NH; h0 += 32) {
        __syncthreads();
        {   // u tile: rows l0..l0+63, cols h0..h0+31 -> transposed u_s[h][l]
            const float* src = u + (size_t)(l0 + row) * (NB * NH) + b * NH + h0 + j0;
            float4 a = *(const float4*)src;
            float4 c = *(const float4*)(src + 4);
            u_s[j0+0][row]=a.x; u_s[j0+1][row]=a.y; u_s[j0+2][row]=a.z; u_s[j0+3][row]=a.w;
            u_s[j0+4][row]=c.x; u_s[j0+5][row]=c.y; u_s[j0+6][row]=c.z; u_s[j0+7][row]=c.w;
        }
        {   // B tiles: rows p0..p0+63, cols h0..h0+31 -> transposed [h][p]
            const float* sr = Btr + (size_t)(p0 + row) * NH + h0 + j0;
            float4 a = *(const float4*)sr;
            float4 c = *(const float4*)(sr + 4);
            br_s[j0+0][row]=a.x; br_s[j0+1][row]=a.y; br_s[j0+2][row]=a.z; br_s[j0+3][row]=a.w;
            br_s[j0+4][row]=c.x; br_s[j0+5][row]=c.y; br_s[j0+6][row]=c.z; br_s[j0+7][row]=c.w;
            const float* si = Bti + (size_t)(p0 + row) * NH + h0 + j0;
            float4 e = *(const float4*)si;
            float4 g = *(const float4*)(si + 4);
            bi_s[j0+0][row]=e.x; bi_s[j0+1][row]=e.y; bi_s[j0+2][row]=e.z; bi_s[j0+3][row]=e.w;
            bi_s[j0+4][row]=g.x; bi_s[j0+5][row]=g.y; bi_s[j0+6][row]=g.z; bi_s[j0+7][row]=g.w;
        }
        __syncthreads();
        #pragma unroll
        for (int hh = 0; hh < 32; ++hh) {
            float u4[4], br4[4], bi4[4];
            *(float4*)u4  = *(const float4*)&u_s[hh][lsub];
            *(float4*)br4 = *(const float4*)&br_s[hh][psub];
            *(float4*)bi4 = *(const float4*)&bi_s[hh][psub];
            #pragma unroll
            for (int i = 0; i < 4; ++i)
                #pragma unroll
                for (int j = 0; j < 4; ++j) {
                    accr[i][j] = fmaf(u4[i], br4[j], accr[i][j]);
                    acci[i][j] = fmaf(u4[i], bi4[j], acci[i][j]);
                }
        }
    }

    // epilogue: multiply by f_p = (w_p - 1)/lambda_p, store complex interleaved
    #pragma unroll
    for (int j = 0; j < 4; ++j) {
        const int p = p0 + psub + j;
        const float Lr = expf(logLr[p]);        // positive
        const float dt = expf(logDt[p]);
        const float li = Lim[p];
        const float ew = expf(-Lr * dt);
        const float ang = li * dt;
        const float wr = ew * cosf(ang), wi = ew * sinf(ang);
        const float nr = wr - 1.0f, ni = wi;
        const float den = Lr * Lr + li * li;    // |lambda|^2
        const float fr = (-nr * Lr + ni * li) / den;
        const float fi = (-ni * Lr - nr * li) / den;
        float* dst = bu + (((size_t)b * NP + p) * SL + l0 + lsub) * 2;
        float4 v0, v1;
        v0.x = fr*accr[0][j] - fi*acci[0][j];  v0.y = fr*acci[0][j] + fi*accr[0][j];
        v0.z = fr*accr[1][j] - fi*acci[1][j];  v0.w = fr*acci[1][j] + fi*accr[1][j];
        v1.x = fr*accr[2][j] - fi*acci[2][j];  v1.y = fr*acci[2][j] + fi*accr[2][j];
        v1.z = fr*accr[3][j] - fi*acci[3][j];  v1.w = fr*acci[3][j] + fi*accr[3][j];
        *(float4*)dst       = v0;
        *(float4*)(dst + 4) = v1;
    }
}

// ---------------------------------------------------------------------------
// Kernel 2: in-place complex scan o[t] = w*o[t-1] + Bu[t] per (b,p).
// One wave per sequence; lane handles 32 contiguous t; Kogge-Stone on carries.
// ---------------------------------------------------------------------------
__global__ __launch_bounds__(256) void k_scan(
    float* __restrict__ bu, const float* __restrict__ logLr,
    const float* __restrict__ Lim, const float* __restrict__ logDt)
{
    const int wave = (blockIdx.x * 256 + threadIdx.x) >> 6;  // 0..8191 = b*NP + p
    const int lane = threadIdx.x & 63;
    const int p = wave & (NP - 1);

    const float Lr = expf(logLr[p]);
    const float dt = expf(logDt[p]);
    const float ang = Lim[p] * dt;
    const float ew = expf(-Lr * dt);
    const float wr = ew * cosf(ang), wi = ew * sinf(ang);

    float* base = bu + ((size_t)wave * SL + lane * 32) * 2;

    float xr[32], xi[32];
    #pragma unroll
    for (int k = 0; k < 32; k += 2) {
        float4 v = *(const float4*)(base + k * 2);
        xr[k] = v.x; xi[k] = v.y; xr[k+1] = v.z; xi[k+1] = v.w;
    }

    // local inclusive scan (zero init), keep prefixes
    float sr = 0.f, si = 0.f;
    #pragma unroll
    for (int k = 0; k < 32; ++k) {
        const float nr = fmaf(wr, sr, fmaf(-wi, si, xr[k]));
        const float ni = fmaf(wr, si, fmaf( wi, sr, xi[k]));
        sr = nr; si = ni; xr[k] = sr; xi[k] = si;
    }

    // A = w^32
    float Ar = wr, Ai = wi;
    #pragma unroll
    for (int q = 0; q < 5; ++q) { const float t = Ar*Ar - Ai*Ai; Ai = 2.f*Ar*Ai; Ar = t; }

    // Kogge-Stone inclusive prefix over lane carries: S_l = A*S_{l-1} + c_l
    float cr = sr, ci = si;
    #pragma unroll
    for (int d = 1; d < 64; d <<= 1) {
        const float ur = __shfl_up(cr, d);
        const float ui = __shfl_up(ci, d);
        if (lane >= d) {
            cr += Ar * ur - Ai * ui;
            ci += Ar * ui + Ai * ur;
        }
        const float t = Ar*Ar - Ai*Ai; Ai = 2.f*Ar*Ai; Ar = t;
    }

    // carry into this lane = inclusive prefix of previous lane
    float pr = __shfl_up(cr, 1);
    float pi = __shfl_up(ci, 1);
    if (lane == 0) { pr = 0.f; pi = 0.f; }

    // apply: x[k] += w^(k+1) * carry
    float mr = pr, mi = pi;
    #pragma unroll
    for (int k = 0; k < 32; ++k) {
        const float t = wr*mr - wi*mi;
        mi = wr*mi + wi*mr; mr = t;
        xr[k] += mr; xi[k] += mi;
    }

    #pragma unroll
    for (int k = 0; k < 32; k += 2) {
        float4 v = { xr[k], xi[k], xr[k+1], xi[k+1] };
        *(float4*)(base + k * 2) = v;
    }
}

// ---------------------------------------------------------------------------
// Kernel 3: out[l,b,h] = sum_p (Cr[h,p]*o_r[b,p,l] - Ci[h,p]*o_i[b,p,l]) + D[h]*u[l,b,h]
// Block: 256 thr, tile l=64 x h=64, K=256 in chunks of 32. 4l x 4h per thread.
// ---------------------------------------------------------------------------
__global__ __launch_bounds__(256) void k_out(
    const float* __restrict__ o, const float* __restrict__ Ctr,
    const float* __restrict__ Cti, const float* __restrict__ D,
    const float* __restrict__ u, float* __restrict__ out)
{
    __shared__ __attribute__((aligned(16))) float or_s[32][68];  // [p][l]
    __shared__ __attribute__((aligned(16))) float oi_s[32][68];  // [p][l]
    __shared__ __attribute__((aligned(16))) float cr_s[32][68];  // [p][h]
    __shared__ __attribute__((aligned(16))) float ci_s[32][68];  // [p][h]

    const int l0 = blockIdx.x * 64;
    const int h0 = blockIdx.y * 64;
    const int b  = blockIdx.z;
    const int tid = threadIdx.x;
    const int lsub = (tid & 15) * 4;
    const int hsub = (tid >> 4) * 4;

    float acc[4][4];   // [l][h]
    #pragma unroll
    for (int i = 0; i < 4; ++i)
        #pragma unroll
        for (int j = 0; j < 4; ++j) acc[i][j] = 0.f;

    for (int p0 = 0; p0 < NP; p0 += 32) {
        __syncthreads();
        {   // o chunk: 32 p-rows x 64 l complex -> split r/i, [p][l]
            const int prow = tid >> 3;          // 0..31
            const int lj = (tid & 7) * 8;       // 8 complex each
            const float* src = o + (((size_t)b * NP + p0 + prow) * SL + l0 + lj) * 2;
            float4 a = *(const float4*)(src + 0);
            float4 c = *(const float4*)(src + 4);
            float4 e = *(const float4*)(src + 8);
            float4 g = *(const float4*)(src + 12);
            or_s[prow][lj+0]=a.x; oi_s[prow][lj+0]=a.y;
            or_s[prow][lj+1]=a.z; oi_s[prow][lj+1]=a.w;
            or_s[prow][lj+2]=c.x; oi_s[prow][lj+2]=c.y;
            or_s[prow][lj+3]=c.z; oi_s[prow][lj+3]=c.w;
            or_s[prow][lj+4]=e.x; oi_s[prow][lj+4]=e.y;
            or_s[prow][lj+5]=e.z; oi_s[prow][lj+5]=e.w;
            or_s[prow][lj+6]=g.x; oi_s[prow][lj+6]=g.y;
            or_s[prow][lj+7]=g.z; oi_s[prow][lj+7]=g.w;
        }
        {   // C chunk: h rows h0..h0+63, p cols p0..p0+31 -> transposed [p][h]
            const int hrow = tid >> 2;          // 0..63
            const int pj = (tid & 3) * 8;       // 0,8,16,24
            const float* sr = Ctr + (size_t)(h0 + hrow) * NP + p0 + pj;
            float4 a = *(const float4*)sr;
            float4 c = *(const float4*)(sr + 4);
            cr_s[pj+0][hrow]=a.x; cr_s[pj+1][hrow]=a.y; cr_s[pj+2][hrow]=a.z; cr_s[pj+3][hrow]=a.w;
            cr_s[pj+4][hrow]=c.x; cr_s[pj+5][hrow]=c.y; cr_s[pj+6][hrow]=c.z; cr_s[pj+7][hrow]=c.w;
            const float* si = Cti + (size_t)(h0 + hrow) * NP + p0 + pj;
            float4 e = *(const float4*)si;
            float4 g = *(const float4*)(si + 4);
            ci_s[pj+0][hrow]=e.x; ci_s[pj+1][hrow]=e.y; ci_s[pj+2][hrow]=e.z; ci_s[pj+3][hrow]=e.w;
            ci_s[pj+4][hrow]=g.x; ci_s[pj+5][hrow]=g.y; ci_s[pj+6][hrow]=g.z; ci_s[pj+7][hrow]=g.w;
        }
        __syncthreads();
        #pragma unroll
        for (int pp = 0; pp < 32; ++pp) {
            float or4[4], oi4[4], cr4[4], ci4[4];
            *(float4*)or4 = *(const float4*)&or_s[pp][lsub];
            *(float4*)oi4 = *(const float4*)&oi_s[pp][lsub];
            *(float4*)cr4 = *(const float4*)&cr_s[pp][hsub];
            *(float4*)ci4 = *(const float4*)&ci_s[pp][hsub];
            #pragma unroll
            for (int i = 0; i < 4; ++i)
                #pragma unroll
                for (int j = 0; j < 4; ++j) {
                    acc[i][j] = fmaf(or4[i],  cr4[j], acc[i][j]);
                    acc[i][j] = fmaf(-oi4[i], ci4[j], acc[i][j]);
                }
        }
    }

    // epilogue: + D[h]*u, store
    float d4[4];
    *(float4*)d4 = *(const float4*)&D[h0 + hsub];
    #pragma unroll
    for (int i = 0; i < 4; ++i) {
        const int l = l0 + lsub + i;
        const size_t off = (size_t)l * (NB * NH) + b * NH + h0 + hsub;
        float4 uv = *(const float4*)(u + off);
        float4 ov;
        ov.x = acc[i][0] + d4[0] * uv.x;
        ov.y = acc[i][1] + d4[1] * uv.y;
        ov.z = acc[i][2] + d4[2] * uv.z;
        ov.w = acc[i][3] + d4[3] * uv.w;
        *(float4*)(out + off) = ov;
    }
}

extern "C" void kernel_launch(void* const* d_in, const int* in_sizes, int n_in,
                              void* d_out, int out_size, void* d_ws, size_t ws_size,
                              hipStream_t stream)
{
    const float* u     = (const float*)d_in[0];
    const float* logLr = (const float*)d_in[1];
    const float* Lim   = (const float*)d_in[2];
    const float* Btr   = (const float*)d_in[3];
    const float* Bti   = (const float*)d_in[4];
    const float* Ctr   = (const float*)d_in[5];
    const float* Cti   = (const float*)d_in[6];
    const float* D     = (const float*)d_in[7];
    const float* logDt = (const float*)d_in[8];
    float* out = (float*)d_out;
    float* bu  = (float*)d_ws;   // needs NB*NP*SL*2*4 = 134,217,728 bytes

    k_bu  <<<dim3(SL/64, NP/64, NB), 256, 0, stream>>>(u, Btr, Bti, logLr, Lim, logDt, bu);
    k_scan<<<dim3((NB*NP)/4),        256, 0, stream>>>(bu, logLr, Lim, logDt);
    k_out <<<dim3(SL/64, NH/64, NB), 256, 0, stream>>>(bu, Ctr, Cti, D, u, out);
}

// Round 2
// 245.033 us; speedup vs baseline: 1.5544x; 1.5544x over previous
//
#include <hip/hip_runtime.h>
#include <math.h>

#define SL 2048   // sequence length L
#define NB 32     // batch
#define NH 128    // feature dim H
#define NP 256    // state dim P (complex)
#define NP2 512   // interleaved real/imag columns

typedef short bf16x8 __attribute__((ext_vector_type(8)));
typedef float f32x4  __attribute__((ext_vector_type(4)));

static __device__ __forceinline__ unsigned short f2bf(float x) {
    unsigned u = __float_as_uint(x);
    return (unsigned short)((u + 0x7fffu + ((u >> 16) & 1u)) >> 16);  // RNE
}
static __device__ __forceinline__ float bf2f(unsigned short h) {
    return __uint_as_float(((unsigned)h) << 16);
}
static __device__ __forceinline__ void discretize(
    const float* __restrict__ logLr, const float* __restrict__ Lim,
    const float* __restrict__ logDt, int p, float& wr, float& wi)
{
    const float Lr = expf(logLr[p]);
    const float dt = expf(logDt[p]);
    const float ew = expf(-Lr * dt);
    const float ang = Lim[p] * dt;
    wr = ew * cosf(ang); wi = ew * sinf(ang);
}

// ---------------------------------------------------------------------------
// k0: pack Bhat[p'=512][h=128] = f_p * B_tilde (interleaved re/im rows) and
//     Chat[h=128][p'=512] = [Cr, -Ci] interleaved cols, both bf16.
// ---------------------------------------------------------------------------
__global__ __launch_bounds__(256) void k0(
    const float* __restrict__ logLr, const float* __restrict__ Lim,
    const float* __restrict__ logDt,
    const float* __restrict__ Br, const float* __restrict__ Bi,
    const float* __restrict__ Cr, const float* __restrict__ Ci,
    unsigned short* __restrict__ Bhat, unsigned short* __restrict__ Chat)
{
    const int tid = blockIdx.x * 256 + threadIdx.x;  // 32768 = P*H
    const int p = tid >> 7, h = tid & 127;
    float wr, wi; discretize(logLr, Lim, logDt, p, wr, wi);
    const float Lr = expf(logLr[p]), li = Lim[p];
    const float nr = wr - 1.0f, ni = wi;
    const float den = Lr * Lr + li * li;
    const float fr = (-nr * Lr + ni * li) / den;
    const float fi = (-ni * Lr - nr * li) / den;
    const float br = Br[p * NH + h], bi = Bi[p * NH + h];
    Bhat[(size_t)(2 * p)     * NH + h] = f2bf(fr * br - fi * bi);
    Bhat[(size_t)(2 * p + 1) * NH + h] = f2bf(fr * bi + fi * br);
    Chat[(size_t)h * NP2 + 2 * p]     = f2bf(Cr[h * NP + p]);
    Chat[(size_t)h * NP2 + 2 * p + 1] = f2bf(-Ci[h * NP + p]);
}

// ---------------------------------------------------------------------------
// g1: bu[b][l][p'] (bf16) = Bhat (512 x 128) * u^T (128 x l) per batch.
// MFMA 16x16x32 bf16, no LDS: A-frags from L2-resident Bhat, B-frags direct
// global u (fp32 -> bf16 in-reg). Block: M=512 (4 waves x 128), N=32 l.
// ---------------------------------------------------------------------------
__global__ __launch_bounds__(256) void g1(
    const float* __restrict__ u, const unsigned short* __restrict__ Bhat,
    unsigned short* __restrict__ bu)
{
    const int l0 = blockIdx.x * 32;
    const int b  = blockIdx.y;
    const int wave = threadIdx.x >> 6, lane = threadIdx.x & 63;
    const int q = lane >> 4, c = lane & 15;
    const int pbase = wave * 128;

    f32x4 acc[8][2];
    #pragma unroll
    for (int mt = 0; mt < 8; ++mt)
        #pragma unroll
        for (int nt = 0; nt < 2; ++nt) acc[mt][nt] = (f32x4){0.f, 0.f, 0.f, 0.f};

    #pragma unroll
    for (int kk = 0; kk < 4; ++kk) {
        const int k0 = kk * 32;
        bf16x8 af[8];
        #pragma unroll
        for (int mt = 0; mt < 8; ++mt)
            af[mt] = *(const bf16x8*)(Bhat + (size_t)(pbase + 16 * mt + c) * NH + k0 + 8 * q);
        bf16x8 bfr[2];
        #pragma unroll
        for (int nt = 0; nt < 2; ++nt) {
            const float* up = u + (size_t)(l0 + 16 * nt + c) * (NB * NH) + b * NH + k0 + 8 * q;
            float4 x = *(const float4*)up;
            float4 y = *(const float4*)(up + 4);
            bf16x8 t;
            t[0] = (short)f2bf(x.x); t[1] = (short)f2bf(x.y);
            t[2] = (short)f2bf(x.z); t[3] = (short)f2bf(x.w);
            t[4] = (short)f2bf(y.x); t[5] = (short)f2bf(y.y);
            t[6] = (short)f2bf(y.z); t[7] = (short)f2bf(y.w);
            bfr[nt] = t;
        }
        #pragma unroll
        for (int mt = 0; mt < 8; ++mt)
            #pragma unroll
            for (int nt = 0; nt < 2; ++nt)
                acc[mt][nt] = __builtin_amdgcn_mfma_f32_16x16x32_bf16(af[mt], bfr[nt], acc[mt][nt], 0, 0, 0);
    }

    // D layout: col(n=l)=lane&15, row(m=p')=4q+reg -> lane's 4 regs are 4
    // consecutive p' in the l-major layout: 8-B packed bf16 stores.
    #pragma unroll
    for (int mt = 0; mt < 8; ++mt)
        #pragma unroll
        for (int nt = 0; nt < 2; ++nt) {
            const int l  = l0 + 16 * nt + c;
            const int pp = pbase + 16 * mt + 4 * q;
            ushort4 st;
            st.x = f2bf(acc[mt][nt][0]); st.y = f2bf(acc[mt][nt][1]);
            st.z = f2bf(acc[mt][nt][2]); st.w = f2bf(acc[mt][nt][3]);
            *(ushort4*)(bu + ((size_t)(b * SL + l)) * NP2 + pp) = st;
        }
}

// ---------------------------------------------------------------------------
// s1: per-chunk carries. Thread owns one complex p; block covers all 256 p
// for one (b, 64-l chunk). Rows are 1 KB, fully coalesced.
// carry[b][m][p] = sum_k w^(63-k) * bu[64m+k]
// ---------------------------------------------------------------------------
__global__ __launch_bounds__(256) void s1(
    const unsigned* __restrict__ bu32, const float* __restrict__ logLr,
    const float* __restrict__ Lim, const float* __restrict__ logDt,
    float2* __restrict__ carry)
{
    const int b = blockIdx.x, m = blockIdx.y, p = threadIdx.x;
    float wr, wi; discretize(logLr, Lim, logDt, p, wr, wi);
    const unsigned* row = bu32 + (size_t)(b * SL + m * 64) * (NP2 / 2) + p;
    float sr = 0.f, si = 0.f;
    #pragma unroll 8
    for (int k = 0; k < 64; ++k) {
        const unsigned v = row[(size_t)k * (NP2 / 2)];
        const float xr = bf2f((unsigned short)(v & 0xffffu));
        const float xi = bf2f((unsigned short)(v >> 16));
        const float tr = wr * sr - wi * si + xr;
        const float ti = wr * si + wi * sr + xi;
        sr = tr; si = ti;
    }
    carry[(size_t)(b * 32 + m) * NP + p] = make_float2(sr, si);
}

// ---------------------------------------------------------------------------
// s2: scan carries across the 32 chunks: C[m] = state ENTERING chunk m.
// One block per b, one thread per p.
// ---------------------------------------------------------------------------
__global__ __launch_bounds__(256) void s2(
    const float2* __restrict__ carry, const float* __restrict__ logLr,
    const float* __restrict__ Lim, const float* __restrict__ logDt,
    float2* __restrict__ C)
{
    const int b = blockIdx.x, p = threadIdx.x;
    float wr, wi; discretize(logLr, Lim, logDt, p, wr, wi);
    float Wr = wr, Wi = wi;
    #pragma unroll
    for (int t = 0; t < 6; ++t) { const float r = Wr * Wr - Wi * Wi; Wi = 2.f * Wr * Wi; Wr = r; }  // w^64
    float sr = 0.f, si = 0.f;
    for (int m = 0; m < 32; ++m) {
        C[(size_t)(b * 32 + m) * NP + p] = make_float2(sr, si);
        const float2 cv = carry[(size_t)(b * 32 + m) * NP + p];
        const float tr = Wr * sr - Wi * si + cv.x;
        const float ti = Wr * si + Wi * sr + cv.y;
        sr = tr; si = ti;
    }
}

// ---------------------------------------------------------------------------
// s3: replay chunk with true entering state, in-place bu -> o (bf16).
// ---------------------------------------------------------------------------
__global__ __launch_bounds__(256) void s3(
    unsigned* __restrict__ bu32, const float* __restrict__ logLr,
    const float* __restrict__ Lim, const float* __restrict__ logDt,
    const float2* __restrict__ C)
{
    const int b = blockIdx.x, m = blockIdx.y, p = threadIdx.x;
    float wr, wi; discretize(logLr, Lim, logDt, p, wr, wi);
    unsigned* row = bu32 + (size_t)(b * SL + m * 64) * (NP2 / 2) + p;
    const float2 c0 = C[(size_t)(b * 32 + m) * NP + p];
    float sr = c0.x, si = c0.y;
    #pragma unroll 8
    for (int k = 0; k < 64; ++k) {
        const unsigned v = row[(size_t)k * (NP2 / 2)];
        const float xr = bf2f((unsigned short)(v & 0xffffu));
        const float xi = bf2f((unsigned short)(v >> 16));
        const float tr = wr * sr - wi * si + xr;
        const float ti = wr * si + wi * sr + xi;
        sr = tr; si = ti;
        row[(size_t)k * (NP2 / 2)] = (unsigned)f2bf(sr) | ((unsigned)f2bf(si) << 16);
    }
}

// ---------------------------------------------------------------------------
// g2: out[l][b][h] = Re(C * o) + D .* u.
// MFMA 16x16x32: A = Chat (h x 512) from L2, B = o[b][l][p'] direct global
// (k = p' contiguous). Block: M=128 h x N=64 l, waves 2x2.
// ---------------------------------------------------------------------------
__global__ __launch_bounds__(256) void g2(
    const unsigned short* __restrict__ o, const unsigned short* __restrict__ Chat,
    const float* __restrict__ Dv, const float* __restrict__ u,
    float* __restrict__ out)
{
    const int b = blockIdx.y;
    const int wave = threadIdx.x >> 6, lane = threadIdx.x & 63;
    const int q = lane >> 4, c = lane & 15;
    const int wm = wave >> 1, wn = wave & 1;
    const int hbase = wm * 64;
    const int l0 = blockIdx.x * 64 + wn * 32;

    f32x4 acc[4][2];
    #pragma unroll
    for (int mt = 0; mt < 4; ++mt)
        #pragma unroll
        for (int nt = 0; nt < 2; ++nt) acc[mt][nt] = (f32x4){0.f, 0.f, 0.f, 0.f};

    #pragma unroll 4
    for (int kk = 0; kk < 16; ++kk) {
        const int k0 = kk * 32;
        bf16x8 af[4];
        #pragma unroll
        for (int mt = 0; mt < 4; ++mt)
            af[mt] = *(const bf16x8*)(Chat + (size_t)(hbase + 16 * mt + c) * NP2 + k0 + 8 * q);
        bf16x8 bfr[2];
        #pragma unroll
        for (int nt = 0; nt < 2; ++nt)
            bfr[nt] = *(const bf16x8*)(o + ((size_t)(b * SL + l0 + 16 * nt + c)) * NP2 + k0 + 8 * q);
        #pragma unroll
        for (int mt = 0; mt < 4; ++mt)
            #pragma unroll
            for (int nt = 0; nt < 2; ++nt)
                acc[mt][nt] = __builtin_amdgcn_mfma_f32_16x16x32_bf16(af[mt], bfr[nt], acc[mt][nt], 0, 0, 0);
    }

    #pragma unroll
    for (int mt = 0; mt < 4; ++mt) {
        const int h4 = hbase + 16 * mt + 4 * q;
        const float4 dd = *(const float4*)(Dv + h4);
        #pragma unroll
        for (int nt = 0; nt < 2; ++nt) {
            const int l = l0 + 16 * nt + c;
            const size_t off = ((size_t)l * NB + b) * NH + h4;
            const float4 uu = *(const float4*)(u + off);
            float4 ov;
            ov.x = acc[mt][nt][0] + dd.x * uu.x;
            ov.y = acc[mt][nt][1] + dd.y * uu.y;
            ov.z = acc[mt][nt][2] + dd.z * uu.z;
            ov.w = acc[mt][nt][3] + dd.w * uu.w;
            *(float4*)(out + off) = ov;
        }
    }
}

extern "C" void kernel_launch(void* const* d_in, const int* in_sizes, int n_in,
                              void* d_out, int out_size, void* d_ws, size_t ws_size,
                              hipStream_t stream)
{
    const float* u     = (const float*)d_in[0];
    const float* logLr = (const float*)d_in[1];
    const float* Lim   = (const float*)d_in[2];
    const float* Btr   = (const float*)d_in[3];
    const float* Bti   = (const float*)d_in[4];
    const float* Ctr   = (const float*)d_in[5];
    const float* Cti   = (const float*)d_in[6];
    const float* D     = (const float*)d_in[7];
    const float* logDt = (const float*)d_in[8];
    float* out = (float*)d_out;

    // workspace layout (total ~71.6 MB)
    char* ws = (char*)d_ws;
    unsigned short* bu    = (unsigned short*)ws;                         // 67,108,864 B
    float2*         carry = (float2*)(ws + 67108864);                    //  2,097,152 B
    float2*         Cst   = (float2*)(ws + 69206016);                    //  2,097,152 B
    unsigned short* Bhat  = (unsigned short*)(ws + 71303168);            //    131,072 B
    unsigned short* Chat  = (unsigned short*)(ws + 71434240);            //    131,072 B

    k0<<<dim3((NP * NH) / 256), 256, 0, stream>>>(logLr, Lim, logDt, Btr, Bti, Ctr, Cti, Bhat, Chat);
    g1<<<dim3(SL / 32, NB), 256, 0, stream>>>(u, Bhat, bu);
    s1<<<dim3(NB, SL / 64), 256, 0, stream>>>((const unsigned*)bu, logLr, Lim, logDt, carry);
    s2<<<dim3(NB), 256, 0, stream>>>(carry, logLr, Lim, logDt, Cst);
    s3<<<dim3(NB, SL / 64), 256, 0, stream>>>((unsigned*)bu, logLr, Lim, logDt, Cst);
    g2<<<dim3(SL / 64, NB), 256, 0, stream>>>(bu, Chat, D, u, out);
}

// Round 3
// 223.692 us; speedup vs baseline: 1.7027x; 1.0954x over previous
//
#include <hip/hip_runtime.h>
#include <math.h>

#define SL 2048   // sequence length L
#define NB 32     // batch
#define NH 128    // feature dim H
#define NP 256    // state dim P (complex)
#define NP2 512   // interleaved real/imag columns

typedef short bf16x8 __attribute__((ext_vector_type(8)));
typedef float f32x4  __attribute__((ext_vector_type(4)));

static __device__ __forceinline__ unsigned short f2bf(float x) {
    unsigned u = __float_as_uint(x);
    return (unsigned short)((u + 0x7fffu + ((u >> 16) & 1u)) >> 16);  // RNE
}
static __device__ __forceinline__ float bf2f(unsigned short h) {
    return __uint_as_float(((unsigned)h) << 16);
}
static __device__ __forceinline__ void discretize(
    const float* __restrict__ logLr, const float* __restrict__ Lim,
    const float* __restrict__ logDt, int p, float& wr, float& wi)
{
    const float Lr = expf(logLr[p]);
    const float dt = expf(logDt[p]);
    const float ew = expf(-Lr * dt);
    const float ang = Lim[p] * dt;
    wr = ew * cosf(ang); wi = ew * sinf(ang);
}

// ---------------------------------------------------------------------------
// k0: pack Bhat[p'=512][h=128] = f_p * B_tilde (interleaved re/im rows) and
//     Chat[h=128][p'=512] = [Cr, -Ci] interleaved cols, both bf16.
// ---------------------------------------------------------------------------
__global__ __launch_bounds__(256) void k0(
    const float* __restrict__ logLr, const float* __restrict__ Lim,
    const float* __restrict__ logDt,
    const float* __restrict__ Br, const float* __restrict__ Bi,
    const float* __restrict__ Cr, const float* __restrict__ Ci,
    unsigned short* __restrict__ Bhat, unsigned short* __restrict__ Chat)
{
    const int tid = blockIdx.x * 256 + threadIdx.x;  // 32768 = P*H
    const int p = tid >> 7, h = tid & 127;
    float wr, wi; discretize(logLr, Lim, logDt, p, wr, wi);
    const float Lr = expf(logLr[p]), li = Lim[p];
    const float nr = wr - 1.0f, ni = wi;
    const float den = Lr * Lr + li * li;
    const float fr = (-nr * Lr + ni * li) / den;
    const float fi = (-ni * Lr - nr * li) / den;
    const float br = Br[p * NH + h], bi = Bi[p * NH + h];
    Bhat[(size_t)(2 * p)     * NH + h] = f2bf(fr * br - fi * bi);
    Bhat[(size_t)(2 * p + 1) * NH + h] = f2bf(fr * bi + fi * br);
    Chat[(size_t)h * NP2 + 2 * p]     = f2bf(Cr[h * NP + p]);
    Chat[(size_t)h * NP2 + 2 * p + 1] = f2bf(-Ci[h * NP + p]);
}

// ---------------------------------------------------------------------------
// gA: fused GEMM1 + half-chunk carry.
//   bu[b][l][p'] (bf16) = Bhat (512 x 128) * u^T, l-tile = 32.
//   u tile staged once in LDS (bf16, padded rows). Output tile also stashed
//   in LDS; after barrier each thread scans its complex p over the 32 l:
//   part[b][j][p] = sum_k w^(31-k) x[32j+k],  j = blockIdx.x.
// ---------------------------------------------------------------------------
__global__ __launch_bounds__(256, 3) void gA(
    const float* __restrict__ u, const unsigned short* __restrict__ Bhat,
    const float* __restrict__ logLr, const float* __restrict__ Lim,
    const float* __restrict__ logDt,
    unsigned short* __restrict__ bu, float2* __restrict__ part)
{
    __shared__ unsigned short us[32][136];   // u tile bf16 [l][h], pad 8
    __shared__ unsigned       xs[32][258];   // out tile [l][complex p], pad 2

    const int l0 = blockIdx.x * 32;
    const int b  = blockIdx.y;
    const int tid = threadIdx.x;

    // ---- stage u tile (32 l x 128 h) fp32 -> bf16 LDS ----
    {
        const int lrow = tid >> 3;          // 0..31
        const int hcol = (tid & 7) * 16;    // 0..112
        const float* up = u + (size_t)(l0 + lrow) * (NB * NH) + b * NH + hcol;
        float4 a = *(const float4*)(up + 0);
        float4 c = *(const float4*)(up + 4);
        float4 e = *(const float4*)(up + 8);
        float4 g = *(const float4*)(up + 12);
        ushort4 s0 = { f2bf(a.x), f2bf(a.y), f2bf(a.z), f2bf(a.w) };
        ushort4 s1v = { f2bf(c.x), f2bf(c.y), f2bf(c.z), f2bf(c.w) };
        ushort4 s2v = { f2bf(e.x), f2bf(e.y), f2bf(e.z), f2bf(e.w) };
        ushort4 s3v = { f2bf(g.x), f2bf(g.y), f2bf(g.z), f2bf(g.w) };
        *(ushort4*)&us[lrow][hcol + 0]  = s0;
        *(ushort4*)&us[lrow][hcol + 4]  = s1v;
        *(ushort4*)&us[lrow][hcol + 8]  = s2v;
        *(ushort4*)&us[lrow][hcol + 12] = s3v;
    }
    __syncthreads();

    const int wave = tid >> 6, lane = tid & 63;
    const int q = lane >> 4, c = lane & 15;
    const int pbase = wave * 128;

    f32x4 acc[8][2];
    #pragma unroll
    for (int mt = 0; mt < 8; ++mt)
        #pragma unroll
        for (int nt = 0; nt < 2; ++nt) acc[mt][nt] = (f32x4){0.f, 0.f, 0.f, 0.f};

    #pragma unroll
    for (int kk = 0; kk < 4; ++kk) {
        const int k0 = kk * 32;
        bf16x8 af[8];
        #pragma unroll
        for (int mt = 0; mt < 8; ++mt)
            af[mt] = *(const bf16x8*)(Bhat + (size_t)(pbase + 16 * mt + c) * NH + k0 + 8 * q);
        bf16x8 bfr[2];
        #pragma unroll
        for (int nt = 0; nt < 2; ++nt)
            bfr[nt] = *(const bf16x8*)&us[16 * nt + c][k0 + 8 * q];
        #pragma unroll
        for (int mt = 0; mt < 8; ++mt)
            #pragma unroll
            for (int nt = 0; nt < 2; ++nt)
                acc[mt][nt] = __builtin_amdgcn_mfma_f32_16x16x32_bf16(af[mt], bfr[nt], acc[mt][nt], 0, 0, 0);
    }

    // store tile to global + stash to LDS for the carry scan
    #pragma unroll
    for (int mt = 0; mt < 8; ++mt)
        #pragma unroll
        for (int nt = 0; nt < 2; ++nt) {
            const int lloc = 16 * nt + c;
            const int pp = pbase + 16 * mt + 4 * q;
            ushort4 st;
            st.x = f2bf(acc[mt][nt][0]); st.y = f2bf(acc[mt][nt][1]);
            st.z = f2bf(acc[mt][nt][2]); st.w = f2bf(acc[mt][nt][3]);
            *(ushort4*)(bu + ((size_t)(b * SL + l0 + lloc)) * NP2 + pp) = st;
            uint2 pk;
            pk.x = (unsigned)st.x | ((unsigned)st.y << 16);
            pk.y = (unsigned)st.z | ((unsigned)st.w << 16);
            *(uint2*)&xs[lloc][pp >> 1] = pk;
        }
    __syncthreads();

    // half-chunk carry: thread owns complex p, scan 32 l from LDS
    {
        const int p = tid;
        float wr, wi; discretize(logLr, Lim, logDt, p, wr, wi);
        float sr = 0.f, si = 0.f;
        #pragma unroll
        for (int k = 0; k < 32; ++k) {
            const unsigned v = xs[k][p];
            const float xr = bf2f((unsigned short)(v & 0xffffu));
            const float xi = bf2f((unsigned short)(v >> 16));
            const float tr = wr * sr - wi * si + xr;
            const float ti = wr * si + wi * sr + xi;
            sr = tr; si = ti;
        }
        part[(size_t)(b * (SL / 32) + blockIdx.x) * NP + p] = make_float2(sr, si);
    }
}

// ---------------------------------------------------------------------------
// s2: compose half-chunk carries into state ENTERING each 64-l chunk.
// One block per b, one thread per p.  s <- w^32 s + part[2m]; s <- w^32 s + part[2m+1]
// ---------------------------------------------------------------------------
__global__ __launch_bounds__(256) void s2(
    const float2* __restrict__ part, const float* __restrict__ logLr,
    const float* __restrict__ Lim, const float* __restrict__ logDt,
    float2* __restrict__ C)
{
    const int b = blockIdx.x, p = threadIdx.x;
    float wr, wi; discretize(logLr, Lim, logDt, p, wr, wi);
    float Wr = wr, Wi = wi;
    #pragma unroll
    for (int t = 0; t < 5; ++t) { const float r = Wr * Wr - Wi * Wi; Wi = 2.f * Wr * Wi; Wr = r; }  // w^32
    float sr = 0.f, si = 0.f;
    for (int m = 0; m < 32; ++m) {
        C[(size_t)(b * 32 + m) * NP + p] = make_float2(sr, si);
        const float2 c0 = part[(size_t)(b * 64 + 2 * m) * NP + p];
        float tr = Wr * sr - Wi * si + c0.x;
        float ti = Wr * si + Wi * sr + c0.y;
        const float2 c1 = part[(size_t)(b * 64 + 2 * m + 1) * NP + p];
        sr = Wr * tr - Wi * ti + c1.x;
        si = Wr * ti + Wi * tr + c1.y;
    }
}

// ---------------------------------------------------------------------------
// gB: fused scan-replay + output GEMM per (b, 64-l chunk).
// Phase 1: thread p scans its complex state over 64 l, in-place bu -> o
//          (software-pipelined 8-row batches).
// Phase 2: after barrier, MFMA GEMM out[64 l][128 h] = o(64x512) * Chat^T,
//          o rows re-read through L1/L2 (just written by this block).
// ---------------------------------------------------------------------------
__global__ __launch_bounds__(256) void gB(
    unsigned* __restrict__ bu32, const unsigned short* __restrict__ Chat,
    const float* __restrict__ logLr, const float* __restrict__ Lim,
    const float* __restrict__ logDt, const float2* __restrict__ C,
    const float* __restrict__ Dv, const float* __restrict__ u,
    float* __restrict__ out)
{
    const int m = blockIdx.x, b = blockIdx.y;
    const int tid = threadIdx.x;

    // ---- phase 1: scan ----
    {
        const int p = tid;
        float wr, wi; discretize(logLr, Lim, logDt, p, wr, wi);
        const float2 c0 = C[(size_t)(b * 32 + m) * NP + p];
        float sr = c0.x, si = c0.y;
        unsigned* row = bu32 + (size_t)(b * SL + m * 64) * NP + p;
        unsigned va[8], vb[8];
        #pragma unroll
        for (int j = 0; j < 8; ++j) va[j] = row[(size_t)j * NP];
        #pragma unroll
        for (int k8 = 0; k8 < 8; ++k8) {
            if (k8 < 7) {
                #pragma unroll
                for (int j = 0; j < 8; ++j) vb[j] = row[(size_t)((k8 + 1) * 8 + j) * NP];
            }
            #pragma unroll
            for (int j = 0; j < 8; ++j) {
                const float xr = bf2f((unsigned short)(va[j] & 0xffffu));
                const float xi = bf2f((unsigned short)(va[j] >> 16));
                const float tr = wr * sr - wi * si + xr;
                const float ti = wr * si + wi * sr + xi;
                sr = tr; si = ti;
                row[(size_t)(k8 * 8 + j) * NP] = (unsigned)f2bf(sr) | ((unsigned)f2bf(si) << 16);
            }
            #pragma unroll
            for (int j = 0; j < 8; ++j) va[j] = vb[j];
        }
    }
    __threadfence_block();
    __syncthreads();

    // ---- phase 2: GEMM ----
    const unsigned short* o = (const unsigned short*)bu32;
    const int wave = tid >> 6, lane = tid & 63;
    const int q = lane >> 4, c = lane & 15;
    const int wm = wave >> 1, wn = wave & 1;
    const int hbase = wm * 64;
    const int lbase = m * 64 + wn * 32;

    f32x4 acc[4][2];
    #pragma unroll
    for (int mt = 0; mt < 4; ++mt)
        #pragma unroll
        for (int nt = 0; nt < 2; ++nt) acc[mt][nt] = (f32x4){0.f, 0.f, 0.f, 0.f};

    #pragma unroll 4
    for (int kk = 0; kk < 16; ++kk) {
        const int k0 = kk * 32;
        bf16x8 af[4];
        #pragma unroll
        for (int mt = 0; mt < 4; ++mt)
            af[mt] = *(const bf16x8*)(Chat + (size_t)(hbase + 16 * mt + c) * NP2 + k0 + 8 * q);
        bf16x8 bfr[2];
        #pragma unroll
        for (int nt = 0; nt < 2; ++nt)
            bfr[nt] = *(const bf16x8*)(o + ((size_t)(b * SL + lbase + 16 * nt + c)) * NP2 + k0 + 8 * q);
        #pragma unroll
        for (int mt = 0; mt < 4; ++mt)
            #pragma unroll
            for (int nt = 0; nt < 2; ++nt)
                acc[mt][nt] = __builtin_amdgcn_mfma_f32_16x16x32_bf16(af[mt], bfr[nt], acc[mt][nt], 0, 0, 0);
    }

    #pragma unroll
    for (int mt = 0; mt < 4; ++mt) {
        const int h4 = hbase + 16 * mt + 4 * q;
        const float4 dd = *(const float4*)(Dv + h4);
        #pragma unroll
        for (int nt = 0; nt < 2; ++nt) {
            const int l = lbase + 16 * nt + c;
            const size_t off = ((size_t)l * NB + b) * NH + h4;
            const float4 uu = *(const float4*)(u + off);
            float4 ov;
            ov.x = acc[mt][nt][0] + dd.x * uu.x;
            ov.y = acc[mt][nt][1] + dd.y * uu.y;
            ov.z = acc[mt][nt][2] + dd.z * uu.z;
            ov.w = acc[mt][nt][3] + dd.w * uu.w;
            *(float4*)(out + off) = ov;
        }
    }
}

extern "C" void kernel_launch(void* const* d_in, const int* in_sizes, int n_in,
                              void* d_out, int out_size, void* d_ws, size_t ws_size,
                              hipStream_t stream)
{
    const float* u     = (const float*)d_in[0];
    const float* logLr = (const float*)d_in[1];
    const float* Lim   = (const float*)d_in[2];
    const float* Btr   = (const float*)d_in[3];
    const float* Bti   = (const float*)d_in[4];
    const float* Ctr   = (const float*)d_in[5];
    const float* Cti   = (const float*)d_in[6];
    const float* D     = (const float*)d_in[7];
    const float* logDt = (const float*)d_in[8];
    float* out = (float*)d_out;

    // workspace layout (~73.7 MB)
    char* ws = (char*)d_ws;
    unsigned short* bu   = (unsigned short*)ws;                  // 67,108,864 B
    float2*         part = (float2*)(ws + 67108864);             //  4,194,304 B (32*64*256)
    float2*         Cst  = (float2*)(ws + 71303168);             //  2,097,152 B (32*32*256)
    unsigned short* Bhat = (unsigned short*)(ws + 73400320);     //    131,072 B
    unsigned short* Chat = (unsigned short*)(ws + 73531392);     //    131,072 B

    k0<<<dim3((NP * NH) / 256), 256, 0, stream>>>(logLr, Lim, logDt, Btr, Bti, Ctr, Cti, Bhat, Chat);
    gA<<<dim3(SL / 32, NB), 256, 0, stream>>>(u, Bhat, logLr, Lim, logDt, bu, part);
    s2<<<dim3(NB), 256, 0, stream>>>(part, logLr, Lim, logDt, Cst);
    gB<<<dim3(SL / 64, NB), 256, 0, stream>>>((unsigned*)bu, Chat, logLr, Lim, logDt, Cst, D, u, out);
}

// Round 5
// 220.742 us; speedup vs baseline: 1.7254x; 1.0134x over previous
//
#include <hip/hip_runtime.h>
#include <math.h>

#define SL 2048   // sequence length L
#define NB 32     // batch
#define NH 128    // feature dim H
#define NP 256    // state dim P (complex)
#define NP2 512   // interleaved real/imag columns

typedef short bf16x8 __attribute__((ext_vector_type(8)));
typedef float f32x4  __attribute__((ext_vector_type(4)));

static __device__ __forceinline__ unsigned short f2bf(float x) {
    unsigned u = __float_as_uint(x);
    return (unsigned short)((u + 0x7fffu + ((u >> 16) & 1u)) >> 16);  // RNE
}
static __device__ __forceinline__ float bf2f(unsigned short h) {
    return __uint_as_float(((unsigned)h) << 16);
}
static __device__ __forceinline__ void discretize(
    const float* __restrict__ logLr, const float* __restrict__ Lim,
    const float* __restrict__ logDt, int p, float& wr, float& wi)
{
    const float Lr = expf(logLr[p]);
    const float dt = expf(logDt[p]);
    const float ew = expf(-Lr * dt);
    const float ang = Lim[p] * dt;
    wr = ew * cosf(ang); wi = ew * sinf(ang);
}

// ---------------------------------------------------------------------------
// k0: pack Bhat[p'=512][h=128] = f_p * B_tilde and Chat[h=128][p'=512] =
// [Cr, -Ci] interleaved, both bf16.
// ---------------------------------------------------------------------------
__global__ __launch_bounds__(256) void k0(
    const float* __restrict__ logLr, const float* __restrict__ Lim,
    const float* __restrict__ logDt,
    const float* __restrict__ Br, const float* __restrict__ Bi,
    const float* __restrict__ Cr, const float* __restrict__ Ci,
    unsigned short* __restrict__ Bhat, unsigned short* __restrict__ Chat)
{
    const int tid = blockIdx.x * 256 + threadIdx.x;  // 32768 = P*H
    const int p = tid >> 7, h = tid & 127;
    float wr, wi; discretize(logLr, Lim, logDt, p, wr, wi);
    const float Lr = expf(logLr[p]), li = Lim[p];
    const float nr = wr - 1.0f, ni = wi;
    const float den = Lr * Lr + li * li;
    const float fr = (-nr * Lr + ni * li) / den;
    const float fi = (-ni * Lr - nr * li) / den;
    const float br = Br[p * NH + h], bi = Bi[p * NH + h];
    Bhat[(size_t)(2 * p)     * NH + h] = f2bf(fr * br - fi * bi);
    Bhat[(size_t)(2 * p + 1) * NH + h] = f2bf(fr * bi + fi * br);
    Chat[(size_t)h * NP2 + 2 * p]     = f2bf(Cr[h * NP + p]);
    Chat[(size_t)h * NP2 + 2 * p + 1] = f2bf(-Ci[h * NP + p]);
}

// ---------------------------------------------------------------------------
// gA: GEMM1 with per-wave persistent A-fragments + bu store + 64-l carries.
// Grid (16 seg, 32 b); block owns a 128-l segment = 4 tiles of 32 l.
// A (wave's 128 p' x 128 h of Bhat) loaded ONCE into 32 bf16x8 registers.
// Per tile: u -> LDS (bf16), 64 MFMA/wave, bu store, xs stash (pitch 257),
// 256-thread in-LDS carry scan -> part[b][2*seg + tile/2][p].
// ---------------------------------------------------------------------------
__global__ __launch_bounds__(256, 2) void gA(
    const float* __restrict__ u, const unsigned short* __restrict__ Bhat,
    const float* __restrict__ logLr, const float* __restrict__ Lim,
    const float* __restrict__ logDt,
    unsigned short* __restrict__ bu, float2* __restrict__ part)
{
    __shared__ unsigned short us[32][136];   // u tile bf16 [l][h], pad 8
    __shared__ unsigned xs[32 * 257];        // out tile [l][complex p], pitch 257

    const int seg = blockIdx.x;              // 0..15
    const int b   = blockIdx.y;
    const int tid = threadIdx.x;
    const int wave = tid >> 6, lane = tid & 63;
    const int q = lane >> 4, c = lane & 15;
    const int pbase = wave * 128;

    // persistent A fragments: 32 x bf16x8 = 128 VGPRs
    bf16x8 A[4][8];
    #pragma unroll
    for (int kk = 0; kk < 4; ++kk)
        #pragma unroll
        for (int mt = 0; mt < 8; ++mt)
            A[kk][mt] = *(const bf16x8*)(Bhat + (size_t)(pbase + 16 * mt + c) * NH
                                              + kk * 32 + 8 * q);

    // scan constants for this thread's p = tid
    float wr, wi; discretize(logLr, Lim, logDt, tid, wr, wi);
    float W32r = wr, W32i = wi;
    #pragma unroll
    for (int t = 0; t < 5; ++t) { const float r = W32r * W32r - W32i * W32i;
                                  W32i = 2.f * W32r * W32i; W32r = r; }

    float2 pa = make_float2(0.f, 0.f);

    for (int t = 0; t < 4; ++t) {
        const int l0 = seg * 128 + t * 32;
        __syncthreads();   // prev scan / us reads done
        {   // stage u tile (32 l x 128 h) fp32 -> bf16 LDS
            const int lrow = tid >> 3;
            const int hcol = (tid & 7) * 16;
            const float* up = u + (size_t)(l0 + lrow) * (NB * NH) + b * NH + hcol;
            float4 a = *(const float4*)(up + 0);
            float4 d = *(const float4*)(up + 4);
            float4 e = *(const float4*)(up + 8);
            float4 g = *(const float4*)(up + 12);
            uint4 w0, w1;
            w0.x = (unsigned)f2bf(a.x) | ((unsigned)f2bf(a.y) << 16);
            w0.y = (unsigned)f2bf(a.z) | ((unsigned)f2bf(a.w) << 16);
            w0.z = (unsigned)f2bf(d.x) | ((unsigned)f2bf(d.y) << 16);
            w0.w = (unsigned)f2bf(d.z) | ((unsigned)f2bf(d.w) << 16);
            w1.x = (unsigned)f2bf(e.x) | ((unsigned)f2bf(e.y) << 16);
            w1.y = (unsigned)f2bf(e.z) | ((unsigned)f2bf(e.w) << 16);
            w1.z = (unsigned)f2bf(g.x) | ((unsigned)f2bf(g.y) << 16);
            w1.w = (unsigned)f2bf(g.z) | ((unsigned)f2bf(g.w) << 16);
            *(uint4*)&us[lrow][hcol + 0] = w0;
            *(uint4*)&us[lrow][hcol + 8] = w1;
        }
        __syncthreads();

        f32x4 acc[8][2];
        #pragma unroll
        for (int mt = 0; mt < 8; ++mt)
            #pragma unroll
            for (int nt = 0; nt < 2; ++nt) acc[mt][nt] = (f32x4){0.f, 0.f, 0.f, 0.f};

        #pragma unroll
        for (int kk = 0; kk < 4; ++kk) {
            bf16x8 bfr[2];
            #pragma unroll
            for (int nt = 0; nt < 2; ++nt)
                bfr[nt] = *(const bf16x8*)&us[16 * nt + c][kk * 32 + 8 * q];
            #pragma unroll
            for (int mt = 0; mt < 8; ++mt)
                #pragma unroll
                for (int nt = 0; nt < 2; ++nt)
                    acc[mt][nt] = __builtin_amdgcn_mfma_f32_16x16x32_bf16(
                        A[kk][mt], bfr[nt], acc[mt][nt], 0, 0, 0);
        }

        // store bu + stash xs
        #pragma unroll
        for (int mt = 0; mt < 8; ++mt)
            #pragma unroll
            for (int nt = 0; nt < 2; ++nt) {
                const int rw = 16 * nt + c;               // local l row
                const int pp = pbase + 16 * mt + 4 * q;   // p' base
                ushort4 st;
                st.x = f2bf(acc[mt][nt][0]); st.y = f2bf(acc[mt][nt][1]);
                st.z = f2bf(acc[mt][nt][2]); st.w = f2bf(acc[mt][nt][3]);
                *(ushort4*)(bu + ((size_t)(b * SL + l0 + rw)) * NP2 + pp) = st;
                const int col = (pp >> 1);                // complex index
                xs[rw * 257 + col]     = (unsigned)st.x | ((unsigned)st.y << 16);
                xs[rw * 257 + col + 1] = (unsigned)st.z | ((unsigned)st.w << 16);
            }
        __syncthreads();

        // carry-only scan of column p = tid over 32 rows
        {
            float sr = 0.f, si = 0.f;
            unsigned va[8], vb[8];
            #pragma unroll
            for (int j = 0; j < 8; ++j) va[j] = xs[j * 257 + tid];
            #pragma unroll
            for (int k8 = 0; k8 < 4; ++k8) {
                if (k8 < 3) {
                    #pragma unroll
                    for (int j = 0; j < 8; ++j) vb[j] = xs[((k8 + 1) * 8 + j) * 257 + tid];
                }
                #pragma unroll
                for (int j = 0; j < 8; ++j) {
                    const float xr = bf2f((unsigned short)(va[j] & 0xffffu));
                    const float xi = bf2f((unsigned short)(va[j] >> 16));
                    const float tr = wr * sr - wi * si + xr;
                    const float ti = wr * si + wi * sr + xi;
                    sr = tr; si = ti;
                }
                #pragma unroll
                for (int j = 0; j < 8; ++j) va[j] = vb[j];
            }
            if ((t & 1) == 0) {
                pa = make_float2(sr, si);
            } else {
                const float cr2 = W32r * pa.x - W32i * pa.y + sr;
                const float ci2 = W32r * pa.y + W32i * pa.x + si;
                part[((size_t)b * 32 + 2 * seg + (t >> 1)) * NP + tid] =
                    make_float2(cr2, ci2);
            }
        }
    }
}

// ---------------------------------------------------------------------------
// s2: scan 64-l chunk carries -> state ENTERING each chunk (w^64 composition).
// ---------------------------------------------------------------------------
__global__ __launch_bounds__(256) void s2(
    const float2* __restrict__ part, const float* __restrict__ logLr,
    const float* __restrict__ Lim, const float* __restrict__ logDt,
    float2* __restrict__ C)
{
    const int b = blockIdx.x, p = threadIdx.x;
    float wr, wi; discretize(logLr, Lim, logDt, p, wr, wi);
    float Wr = wr, Wi = wi;
    #pragma unroll
    for (int t = 0; t < 6; ++t) { const float r = Wr * Wr - Wi * Wi; Wi = 2.f * Wr * Wi; Wr = r; }  // w^64
    float sr = 0.f, si = 0.f;
    for (int m = 0; m < 32; ++m) {
        C[(size_t)(b * 32 + m) * NP + p] = make_float2(sr, si);
        const float2 v = part[(size_t)(b * 32 + m) * NP + p];
        const float tr = Wr * sr - Wi * si + v.x;
        const float ti = Wr * si + Wi * sr + v.y;
        sr = tr; si = ti;
    }
}

// ---------------------------------------------------------------------------
// gB: fused scan-replay + output GEMM per (b, 64-l chunk).
// Phase 1 (wave 0 only): lane owns 4 consecutive p -> uint4 row loads/stores,
// 8-row prefetch (1 KB/instr coalesced, 128 B in flight per lane).
// Phase 2: MFMA GEMM out[64 l][128 h], o re-read through L1/L2.
// ---------------------------------------------------------------------------
__global__ __launch_bounds__(256) void gB(
    unsigned* __restrict__ bu32, const unsigned short* __restrict__ Chat,
    const float* __restrict__ logLr, const float* __restrict__ Lim,
    const float* __restrict__ logDt, const float2* __restrict__ C,
    const float* __restrict__ Dv, const float* __restrict__ u,
    float* __restrict__ out)
{
    const int m = blockIdx.x, b = blockIdx.y;
    const int tid = threadIdx.x;

    if (tid < 64) {
        const int p0 = tid * 4;
        float wr[4], wi[4], sr[4], si[4];
        #pragma unroll
        for (int j = 0; j < 4; ++j) {
            discretize(logLr, Lim, logDt, p0 + j, wr[j], wi[j]);
            const float2 E = C[(size_t)(b * 32 + m) * NP + p0 + j];
            sr[j] = E.x; si[j] = E.y;
        }
        unsigned* base = bu32 + (size_t)(b * SL + m * 64) * NP + p0;
        uint4 va[8], vb[8];
        #pragma unroll
        for (int j = 0; j < 8; ++j) va[j] = *(const uint4*)(base + (size_t)j * NP);
        #pragma unroll
        for (int k8 = 0; k8 < 8; ++k8) {
            if (k8 < 7) {
                #pragma unroll
                for (int j = 0; j < 8; ++j)
                    vb[j] = *(const uint4*)(base + (size_t)((k8 + 1) * 8 + j) * NP);
            }
            #pragma unroll
            for (int j = 0; j < 8; ++j) {
                unsigned vv[4] = { va[j].x, va[j].y, va[j].z, va[j].w };
                #pragma unroll
                for (int e = 0; e < 4; ++e) {
                    const float xr = bf2f((unsigned short)(vv[e] & 0xffffu));
                    const float xi = bf2f((unsigned short)(vv[e] >> 16));
                    const float tr = wr[e] * sr[e] - wi[e] * si[e] + xr;
                    const float ti = wr[e] * si[e] + wi[e] * sr[e] + xi;
                    sr[e] = tr; si[e] = ti;
                    vv[e] = (unsigned)f2bf(tr) | ((unsigned)f2bf(ti) << 16);
                }
                uint4 st = { vv[0], vv[1], vv[2], vv[3] };
                *(uint4*)(base + (size_t)(k8 * 8 + j) * NP) = st;
            }
            #pragma unroll
            for (int j = 0; j < 8; ++j) va[j] = vb[j];
        }
    }
    __threadfence_block();
    __syncthreads();

    // ---- phase 2: GEMM ----
    const unsigned short* o = (const unsigned short*)bu32;
    const int wave = tid >> 6, lane = tid & 63;
    const int q = lane >> 4, c = lane & 15;
    const int wm = wave >> 1, wn = wave & 1;
    const int hbase = wm * 64;
    const int lbase = m * 64 + wn * 32;

    f32x4 acc[4][2];
    #pragma unroll
    for (int mt = 0; mt < 4; ++mt)
        #pragma unroll
        for (int nt = 0; nt < 2; ++nt) acc[mt][nt] = (f32x4){0.f, 0.f, 0.f, 0.f};

    #pragma unroll 4
    for (int kk = 0; kk < 16; ++kk) {
        bf16x8 af[4];
        #pragma unroll
        for (int mt = 0; mt < 4; ++mt)
            af[mt] = *(const bf16x8*)(Chat + (size_t)(hbase + 16 * mt + c) * NP2
                                           + kk * 32 + 8 * q);
        bf16x8 bfr[2];
        #pragma unroll
        for (int nt = 0; nt < 2; ++nt)
            bfr[nt] = *(const bf16x8*)(o + ((size_t)(b * SL + lbase + 16 * nt + c)) * NP2
                                         + kk * 32 + 8 * q);
        #pragma unroll
        for (int mt = 0; mt < 4; ++mt)
            #pragma unroll
            for (int nt = 0; nt < 2; ++nt)
                acc[mt][nt] = __builtin_amdgcn_mfma_f32_16x16x32_bf16(
                    af[mt], bfr[nt], acc[mt][nt], 0, 0, 0);
    }

    #pragma unroll
    for (int mt = 0; mt < 4; ++mt) {
        const int h4 = hbase + 16 * mt + 4 * q;
        const float4 dd = *(const float4*)(Dv + h4);
        #pragma unroll
        for (int nt = 0; nt < 2; ++nt) {
            const int l = lbase + 16 * nt + c;
            const size_t off = ((size_t)l * NB + b) * NH + h4;
            const float4 uu = *(const float4*)(u + off);
            float4 ov;
            ov.x = acc[mt][nt][0] + dd.x * uu.x;
            ov.y = acc[mt][nt][1] + dd.y * uu.y;
            ov.z = acc[mt][nt][2] + dd.z * uu.z;
            ov.w = acc[mt][nt][3] + dd.w * uu.w;
            *(float4*)(out + off) = ov;
        }
    }
}

extern "C" void kernel_launch(void* const* d_in, const int* in_sizes, int n_in,
                              void* d_out, int out_size, void* d_ws, size_t ws_size,
                              hipStream_t stream)
{
    const float* u     = (const float*)d_in[0];
    const float* logLr = (const float*)d_in[1];
    const float* Lim   = (const float*)d_in[2];
    const float* Btr   = (const float*)d_in[3];
    const float* Bti   = (const float*)d_in[4];
    const float* Ctr   = (const float*)d_in[5];
    const float* Cti   = (const float*)d_in[6];
    const float* Dv    = (const float*)d_in[7];
    const float* logDt = (const float*)d_in[8];
    float* out = (float*)d_out;

    char* ws = (char*)d_ws;
    unsigned short* bu   = (unsigned short*)ws;                  // 67,108,864 B
    float2*         part = (float2*)(ws + 67108864);             //  2,097,152 B
    float2*         Cst  = (float2*)(ws + 69206016);             //  2,097,152 B
    unsigned short* Bhat = (unsigned short*)(ws + 71303168);     //    131,072 B
    unsigned short* Chat = (unsigned short*)(ws + 71434240);     //    131,072 B

    k0<<<dim3((NP * NH) / 256), 256, 0, stream>>>(logLr, Lim, logDt,
                                                  Btr, Bti, Ctr, Cti, Bhat, Chat);
    gA<<<dim3(16, NB), 256, 0, stream>>>(u, Bhat, logLr, Lim, logDt, bu, part);
    s2<<<dim3(NB), 256, 0, stream>>>(part, logLr, Lim, logDt, Cst);
    gB<<<dim3(SL / 64, NB), 256, 0, stream>>>((unsigned*)bu, Chat, logLr, Lim,
                                              logDt, Cst, Dv, u, out);
}